// Round 6
// baseline (4600.689 us; speedup 1.0000x reference)
//
#include <hip/hip_runtime.h>
#include <cmath>

typedef __bf16 bf16;
typedef __bf16 bf16x8 __attribute__((ext_vector_type(8)));
typedef __bf16 bf16x4 __attribute__((ext_vector_type(4)));
typedef float  f32x4  __attribute__((ext_vector_type(4)));

#define MFMA16(a,b,c) __builtin_amdgcn_mfma_f32_16x16x32_bf16(a,b,c,0,0,0)

// async global->LDS, 16B per lane. LDS dest = wave-uniform base + lane*16.
__device__ __forceinline__ void async_ld16(const void* g, void* l) {
  __builtin_amdgcn_global_load_lds((__attribute__((address_space(1))) void*)(g),
                                   (__attribute__((address_space(3))) void*)(l),
                                   16, 0, 0);
}

enum { EPI_PATCH = 0, EPI_BF16 = 1, EPI_RESID = 2, EPI_GELU = 3 };

// -- 8-wave 256x128, ring-2 counted-vmcnt, T2 swizzle, SUPERTILE remap -------
// Staging-BW-bound fix: bytes/FLOP 0.75x of 128^2 (24KB per 2.1 MFLOP).
// Ring-2 keeps LDS at 48KB -> 3 blocks/CU (round 4's ring-3 at 72KB capped 2,
// which killed it). Supertile: bijective XCD chunking + SB=5 bm-supergroups
// (bm_in fastest) so 5 concurrent blocks share one weight panel and their
// A-panels stay L2-resident across the bn sweep; zi slowest separates split-K
// atomic slices temporally. REQUIRES gridDim.x % 5 == 0 (all sites: nbm=25).
template <int EPI>
__global__ __launch_bounds__(512, 4) void gemm256(
    const bf16* __restrict__ A, const bf16* __restrict__ Wt,
    const float* __restrict__ bias, bf16* __restrict__ outB,
    float* __restrict__ outF, int M, int N, int K, int Kc)
{
  __shared__ bf16 As[2][256 * 32];                 // 32 KB
  __shared__ bf16 Bs[2][128 * 32];                 // 16 KB
  const int tid  = threadIdx.x;
  const int lane = tid & 63, wid = tid >> 6;       // wid 0..7
  const int qr   = lane & 15, quad = lane >> 4;
  const int wm   = wid >> 1, wn = wid & 1;         // wave tile 64x64

  // bijective XCD remap + supertile decode
  const int nbm = gridDim.x, nbn = gridDim.y, nz = gridDim.z;
  const int nwg = nbm * nbn * nz;
  const int orig = (blockIdx.z * nbn + blockIdx.y) * nbm + blockIdx.x;
  const int xcd = orig & 7, pos = orig >> 3;
  const int q8 = nwg >> 3, r8 = nwg & 7;
  const int w = (xcd < r8 ? xcd * (q8 + 1) : r8 * (q8 + 1) + (xcd - r8) * q8) + pos;
  constexpr int SB = 5;
  const int sgsz = SB * nbn * nz;
  const int sg = w / sgsz, rem = w % sgsz;
  const int bm = sg * SB + rem % SB;               // bm_in fastest
  const int bn = (rem / SB) % nbn;
  const int zi = rem / (SB * nbn);                 // zi slowest

  const int kbeg = zi * Kc;
  const int kend = min(K, kbeg + Kc);
  // staging: lane covers LDS row wid*16 + (lane>>2) (and +128 for A half 2),
  // slot lane&3 linear; fetch the global column belonging at that slot after
  // the XOR swizzle (slot ^ ((row>>1)&3)).
  const int sr   = wid * 16 + (lane >> 2);         // staged row 0..127
  const int fst  = (lane >> 3) & 3;                // (row>>1)&3 for that row
  const int scol = (((lane & 3) ^ fst)) * 8;       // swizzled global col (elems)
  const int fr   = (qr >> 1) & 3;                  // (row>>1)&3 for read rows

  f32x4 zero4 = {0.f, 0.f, 0.f, 0.f};
  f32x4 acc[4][4];
#pragma unroll
  for (int i = 0; i < 4; i++)
#pragma unroll
    for (int j = 0; j < 4; j++) acc[i][j] = zero4;

  const int ra0 = min(bm * 256 + sr, M - 1);       // clamp ragged M
  const int ra1 = min(bm * 256 + 128 + sr, M - 1);
  const size_t nr = (size_t)(bn * 128 + sr);

  auto stage = [&](int buf, int k0) {   // 3 vmem ops / lane
    async_ld16(A  + (size_t)ra0 * K + k0 + scol, &As[buf][(wid * 16) * 32]);
    async_ld16(A  + (size_t)ra1 * K + k0 + scol, &As[buf][(128 + wid * 16) * 32]);
    async_ld16(Wt + nr * K + k0 + scol,          &Bs[buf][(wid * 16) * 32]);
  };

  const int nt = (kend - kbeg) >> 5;               // >= 6 at every call site
  stage(0, kbeg); stage(1, kbeg + 32);
  int buf = 0;
  for (int t = 0; t < nt; ++t) {
    // wait until THIS step's stage is complete; keep the next one in flight
    if (t + 1 < nt)  asm volatile("s_waitcnt vmcnt(3)" ::: "memory");
    else             asm volatile("s_waitcnt vmcnt(0)" ::: "memory");
    __builtin_amdgcn_s_barrier();                  // all waves' stage-t done
    asm volatile("" ::: "memory");
    bf16x8 af[4], bfr[4];
    const bf16* Ab = &As[buf][0];
    const bf16* Bb = &Bs[buf][0];
#pragma unroll
    for (int mi = 0; mi < 4; mi++)
      af[mi] = *(const bf16x8*)&Ab[(wm * 64 + mi * 16 + qr) * 32 + (quad ^ fr) * 8];
#pragma unroll
    for (int ni = 0; ni < 4; ni++)
      bfr[ni] = *(const bf16x8*)&Bb[(wn * 64 + ni * 16 + qr) * 32 + (quad ^ fr) * 8];
    __builtin_amdgcn_s_setprio(1);
#pragma unroll
    for (int mi = 0; mi < 4; mi++)
#pragma unroll
      for (int ni = 0; ni < 4; ni++)
        acc[mi][ni] = MFMA16(af[mi], bfr[ni], acc[mi][ni]);
    __builtin_amdgcn_s_setprio(0);
    __builtin_amdgcn_sched_barrier(0);             // pin reads+MFMA before reuse
    asm volatile("" ::: "memory");
    __builtin_amdgcn_s_barrier();                  // all waves done reading buf
    asm volatile("" ::: "memory");
    if (t + 2 < nt) stage(buf, kbeg + (t + 2) * 32);
    buf ^= 1;
  }

  // epilogue: C row = quad*4+r, col = lane&15 within each 16x16 tile
#pragma unroll
  for (int mi = 0; mi < 4; mi++) {
#pragma unroll
    for (int ni = 0; ni < 4; ni++) {
      const int row0 = bm * 256 + wm * 64 + mi * 16 + quad * 4;
      const int col  = bn * 128 + wn * 64 + ni * 16 + qr;
      const float bv = (zi == 0) ? bias[col] : 0.f;
#pragma unroll
      for (int r = 0; r < 4; r++) {
        const int row = row0 + r;
        if (row < M) {
          float v = acc[mi][ni][r] + bv;
          if constexpr (EPI == EPI_PATCH) {
            int bb = row / 196, nn = row % 196;
            int orow = bb * 197 + 1 + nn;
            atomicAdd(&outF[(size_t)orow * 768 + col], v);
          } else if constexpr (EPI == EPI_BF16) {
            outB[(size_t)row * N + col] = (bf16)v;
          } else if constexpr (EPI == EPI_GELU) {
            float gel = 0.5f * v * (1.f + erff(v * 0.70710678118f));
            outB[(size_t)row * N + col] = (bf16)gel;
          } else {  // EPI_RESID: h += (acc + bias)
            atomicAdd(&outF[(size_t)row * 768 + col], v);
          }
        }
      }
    }
  }
}

// Attention: one block = (b, head, 64 q-rows). Full K/V in LDS. S=197, dh=64.
// P aliases K's LDS (K dead after scores) -> 67 KB -> 2 blocks/CU.
__global__ __launch_bounds__(256) void attn_kernel(
    const bf16* __restrict__ qkv, bf16* __restrict__ o)
{
  __shared__ __align__(16) char smem[68864];
  bf16 (*Qs)[72]  = (bf16(*)[72])(smem);                 //  9216 B
  bf16 (*Ks)[72]  = (bf16(*)[72])(smem + 9216);          // 29952 B
  bf16 (*Ps)[232] = (bf16(*)[232])(smem + 9216);         // aliases Ks (29696 B)
  bf16 (*Vt)[232] = (bf16(*)[232])(smem + 39168);        // 29696 B

  const int tid  = threadIdx.x;
  const int lane = tid & 63, wid = tid >> 6;
  const int qr   = lane & 15, quad = lane >> 4;
  const int qt   = blockIdx.x & 3, bh = blockIdx.x >> 2;
  const int head = bh % 12, b = bh / 12;
  const int q0   = qt * 64;
  const size_t base = (size_t)b * 197 * 2304 + head * 64;

  // stage Q (clamp rows >196 to 196; garbage rows never stored)
  {
    int r = tid >> 2, cb = (tid & 3) * 16;
    int s = q0 + r; if (s > 196) s = 196;
    const bf16* src = qkv + base + (size_t)s * 2304 + cb;
    *(uint4*)&Qs[r][cb]     = *(const uint4*)src;
    *(uint4*)&Qs[r][cb + 8] = *(const uint4*)(src + 8);
  }
  // stage K rows 0..207 (zeros >=197)
  for (int rr = tid >> 2; rr < 208; rr += 64) {
    int cb = (tid & 3) * 16;
    uint4 v0 = make_uint4(0, 0, 0, 0), v1 = make_uint4(0, 0, 0, 0);
    if (rr < 197) {
      const bf16* src = qkv + base + 768 + (size_t)rr * 2304 + cb;
      v0 = *(const uint4*)src; v1 = *(const uint4*)(src + 8);
    }
    *(uint4*)&Ks[rr][cb] = v0; *(uint4*)&Ks[rr][cb + 8] = v1;
  }
  // stage V transposed [d][key] (zeros for key>=197)
  for (int rr = tid >> 2; rr < 224; rr += 64) {
    int cb = (tid & 3) * 16;
    bf16 tmp[16];
    if (rr < 197) {
      const bf16* src = qkv + base + 1536 + (size_t)rr * 2304 + cb;
      *(uint4*)&tmp[0] = *(const uint4*)src;
      *(uint4*)&tmp[8] = *(const uint4*)(src + 8);
    } else {
#pragma unroll
      for (int j = 0; j < 16; j++) tmp[j] = (bf16)0.f;
    }
#pragma unroll
    for (int j = 0; j < 16; j++) Vt[cb + j][rr] = tmp[j];
  }
  __syncthreads();

  // scores: wave handles q rows [wid*16, wid*16+16)
  bf16x8 qa0 = *(const bf16x8*)&Qs[wid * 16 + qr][quad * 8];
  bf16x8 qa1 = *(const bf16x8*)&Qs[wid * 16 + qr][32 + quad * 8];
  f32x4 zero4 = {0.f, 0.f, 0.f, 0.f};
  f32x4 sc[13];
#pragma unroll
  for (int t = 0; t < 13; t++) sc[t] = zero4;
#pragma unroll
  for (int t = 0; t < 13; t++) {
    bf16x8 kb0 = *(const bf16x8*)&Ks[t * 16 + qr][quad * 8];
    bf16x8 kb1 = *(const bf16x8*)&Ks[t * 16 + qr][32 + quad * 8];
    sc[t] = MFMA16(qa0, kb0, sc[t]);
    sc[t] = MFMA16(qa1, kb1, sc[t]);
  }
  // softmax: lane holds col=16t+qr, row=quad*4+r; row-reduce across 16 lanes
  float mx[4] = {-1e30f, -1e30f, -1e30f, -1e30f};
#pragma unroll
  for (int t = 0; t < 13; t++) {
    bool valid = (t * 16 + qr) < 197;
#pragma unroll
    for (int r = 0; r < 4; r++) {
      float v = sc[t][r] * 0.125f;
      sc[t][r] = v;
      if (valid) mx[r] = fmaxf(mx[r], v);
    }
  }
#pragma unroll
  for (int r = 0; r < 4; r++)
#pragma unroll
    for (int off = 1; off < 16; off <<= 1)
      mx[r] = fmaxf(mx[r], __shfl_xor(mx[r], off, 16));
  float sum[4] = {0.f, 0.f, 0.f, 0.f};
#pragma unroll
  for (int t = 0; t < 13; t++) {
    bool valid = (t * 16 + qr) < 197;
#pragma unroll
    for (int r = 0; r < 4; r++) {
      float e = valid ? __expf(sc[t][r] - mx[r]) : 0.f;
      sc[t][r] = e; sum[r] += e;
    }
  }
#pragma unroll
  for (int r = 0; r < 4; r++) {
#pragma unroll
    for (int off = 1; off < 16; off <<= 1)
      sum[r] += __shfl_xor(sum[r], off, 16);
    sum[r] = 1.f / sum[r];
  }
  __syncthreads();   // all waves done reading Ks; safe to overwrite with Ps
#pragma unroll
  for (int t = 0; t < 13; t++)
#pragma unroll
    for (int r = 0; r < 4; r++)
      Ps[wid * 16 + quad * 4 + r][t * 16 + qr] = (bf16)(sc[t][r] * sum[r]);
  // zero Ps pad cols [208,224): wave covers its own 16 rows
  {
    bf16x4 zz = {(bf16)0.f, (bf16)0.f, (bf16)0.f, (bf16)0.f};
    *(bf16x4*)&Ps[wid * 16 + qr][208 + quad * 4] = zz;
  }
  __syncthreads();

  // PV: O[64 x 64] per wave-tile; K-loop over padded 224 keys
  f32x4 oa[4];
#pragma unroll
  for (int ni = 0; ni < 4; ni++) oa[ni] = zero4;
#pragma unroll
  for (int k0 = 0; k0 < 224; k0 += 32) {
    bf16x8 pa = *(const bf16x8*)&Ps[wid * 16 + qr][k0 + quad * 8];
#pragma unroll
    for (int ni = 0; ni < 4; ni++) {
      bf16x8 vb = *(const bf16x8*)&Vt[ni * 16 + qr][k0 + quad * 8];
      oa[ni] = MFMA16(pa, vb, oa[ni]);
    }
  }
  // store O at [b][s][head][d]
#pragma unroll
  for (int ni = 0; ni < 4; ni++)
#pragma unroll
    for (int r = 0; r < 4; r++) {
      int row = q0 + wid * 16 + quad * 4 + r;
      if (row < 197)
        o[(((size_t)b * 197 + row) * 12 + head) * 64 + ni * 16 + qr] =
            (bf16)oa[ni][r];
    }
}

// LayerNorm over 768, one wave per row, bf16 out
__global__ __launch_bounds__(256) void ln_bf16(
    const float* __restrict__ h, const float* __restrict__ w,
    const float* __restrict__ b, bf16* __restrict__ y, int rows)
{
  int row = blockIdx.x * 4 + (threadIdx.x >> 6);
  int lane = threadIdx.x & 63;
  if (row >= rows) return;
  const float* hr = h + (size_t)row * 768;
  float v[12]; float s = 0.f;
#pragma unroll
  for (int i = 0; i < 12; i++) { v[i] = hr[lane + 64 * i]; s += v[i]; }
#pragma unroll
  for (int off = 32; off >= 1; off >>= 1) s += __shfl_xor(s, off, 64);
  float mean = s * (1.f / 768.f);
  float q = 0.f;
#pragma unroll
  for (int i = 0; i < 12; i++) { float d = v[i] - mean; q += d * d; }
#pragma unroll
  for (int off = 32; off >= 1; off >>= 1) q += __shfl_xor(q, off, 64);
  float rstd = rsqrtf(q * (1.f / 768.f) + 1e-6f);
  bf16* yr = y + (size_t)row * 768;
#pragma unroll
  for (int i = 0; i < 12; i++)
    yr[lane + 64 * i] = (bf16)((v[i] - mean) * rstd * w[lane + 64 * i] + b[lane + 64 * i]);
}

// Final LN on the 32 CLS rows, fp32 out
__global__ __launch_bounds__(256) void ln_final(
    const float* __restrict__ h, const float* __restrict__ w,
    const float* __restrict__ b, float* __restrict__ out)
{
  int bi = blockIdx.x * 4 + (threadIdx.x >> 6);
  int lane = threadIdx.x & 63;
  if (bi >= 32) return;
  const float* hr = h + (size_t)bi * 197 * 768;
  float v[12]; float s = 0.f;
#pragma unroll
  for (int i = 0; i < 12; i++) { v[i] = hr[lane + 64 * i]; s += v[i]; }
#pragma unroll
  for (int off = 32; off >= 1; off >>= 1) s += __shfl_xor(s, off, 64);
  float mean = s * (1.f / 768.f);
  float q = 0.f;
#pragma unroll
  for (int i = 0; i < 12; i++) { float d = v[i] - mean; q += d * d; }
#pragma unroll
  for (int off = 32; off >= 1; off >>= 1) q += __shfl_xor(q, off, 64);
  float rstd = rsqrtf(q * (1.f / 768.f) + 1e-6f);
#pragma unroll
  for (int i = 0; i < 12; i++)
    out[(size_t)bi * 768 + lane + 64 * i] =
        (v[i] - mean) * rstd * w[lane + 64 * i] + b[lane + 64 * i];
}

// [z][R][C] fp32 -> [z][C][R] bf16 (all dims multiples of 32)
__global__ __launch_bounds__(256) void transpose_w(
    const float* __restrict__ in, bf16* __restrict__ out, int R, int C)
{
  __shared__ float t[32][33];
  size_t zoff = (size_t)blockIdx.z * R * C;
  in += zoff; out += zoff;
  int c0 = blockIdx.x * 32, r0 = blockIdx.y * 32;
  int lx = threadIdx.x & 31, ly = threadIdx.x >> 5;  // 32 x 8
#pragma unroll
  for (int i = 0; i < 32; i += 8) t[ly + i][lx] = in[(size_t)(r0 + ly + i) * C + c0 + lx];
  __syncthreads();
#pragma unroll
  for (int i = 0; i < 32; i += 8)
    out[(size_t)(c0 + ly + i) * R + r0 + lx] = (bf16)t[lx][ly + i];
}

__global__ __launch_bounds__(256) void convert_bf16(
    const float* __restrict__ in, bf16* __restrict__ out, int n)
{
  int i = blockIdx.x * 256 + threadIdx.x;
  if (i < n) out[i] = (bf16)in[i];
}

// x(32,3,224,224) -> patches[6272][768] bf16; k = c*256 + iy*16 + ix
__global__ __launch_bounds__(256) void patch_extract(
    const float* __restrict__ x, bf16* __restrict__ patches)
{
  int i = blockIdx.x * 256 + threadIdx.x;
  if (i >= 6272 * 192) return;
  int m = i / 192, kq = (i % 192) * 4;
  int b = m / 196, pp = m % 196, py = pp / 14, px = pp % 14;
  int c = kq >> 8, rem = kq & 255, iy = rem >> 4, ix = rem & 15;
  const float4 v = *(const float4*)&x[(((size_t)(b * 3 + c) * 224 + py * 16 + iy) * 224) + px * 16 + ix];
  bf16x4 pv = {(bf16)v.x, (bf16)v.y, (bf16)v.z, (bf16)v.w};
  *(bf16x4*)&patches[(size_t)m * 768 + kq] = pv;
}

// prefill h: h[b][s][:] = pos[s] (+ cls for s==0); patch GEMM then accumulates
__global__ __launch_bounds__(256) void h_init_full(
    const float* __restrict__ cls, const float* __restrict__ pos,
    float* __restrict__ h)
{
  int i = blockIdx.x * 256 + threadIdx.x;
  if (i >= 6304 * 192) return;
  int row = i / 192, c4 = (i % 192) * 4;
  int s = row % 197;
  float4 pv = *(const float4*)&pos[(size_t)s * 768 + c4];
  if (s == 0) {
    float4 cv = *(const float4*)&cls[c4];
    pv.x += cv.x; pv.y += cv.y; pv.z += cv.z; pv.w += cv.w;
  }
  *(float4*)&h[(size_t)row * 768 + c4] = pv;
}

extern "C" void kernel_launch(void* const* d_in, const int* in_sizes, int n_in,
                              void* d_out, int out_size, void* d_ws, size_t ws_size,
                              hipStream_t stream)
{
  const float* x      = (const float*)d_in[0];
  const float* conv_w = (const float*)d_in[1];
  const float* conv_b = (const float*)d_in[2];
  const float* cls    = (const float*)d_in[3];
  const float* pos    = (const float*)d_in[4];
  const float* ln1_w  = (const float*)d_in[5];
  const float* ln1_b  = (const float*)d_in[6];
  const float* qkv_w  = (const float*)d_in[7];
  const float* qkv_b  = (const float*)d_in[8];
  const float* proj_w = (const float*)d_in[9];
  const float* proj_b = (const float*)d_in[10];
  const float* ln2_w  = (const float*)d_in[11];
  const float* ln2_b  = (const float*)d_in[12];
  const float* fc1_w  = (const float*)d_in[13];
  const float* fc1_b  = (const float*)d_in[14];
  const float* fc2_w  = (const float*)d_in[15];
  const float* fc2_b  = (const float*)d_in[16];
  const float* lnf_w  = (const float*)d_in[17];
  const float* lnf_b  = (const float*)d_in[18];
  float* out = (float*)d_out;
  (void)in_sizes; (void)n_in; (void)out_size; (void)ws_size;

  char* ws = (char*)d_ws;
  size_t off = 0;
  auto alloc = [&](size_t bytes) -> char* {
    char* p = ws + off;
    off += (bytes + 255) & ~(size_t)255;
    return p;
  };

  bf16*  convwB  = (bf16*)alloc((size_t)768 * 768 * 2);
  bf16*  qkvT    = (bf16*)alloc((size_t)12 * 2304 * 768 * 2);
  bf16*  projT   = (bf16*)alloc((size_t)12 * 768 * 768 * 2);
  bf16*  fc1T    = (bf16*)alloc((size_t)12 * 3072 * 768 * 2);
  bf16*  fc2T    = (bf16*)alloc((size_t)12 * 768 * 3072 * 2);
  bf16*  patches = (bf16*)alloc((size_t)6272 * 768 * 2);
  float* h       = (float*)alloc((size_t)6304 * 768 * 4);
  bf16*  y       = (bf16*)alloc((size_t)6304 * 768 * 2);
  bf16*  qkvB    = (bf16*)alloc((size_t)6304 * 2304 * 2);
  bf16*  obuf    = (bf16*)alloc((size_t)6304 * 768 * 2);
  bf16*  g       = (bf16*)alloc((size_t)6304 * 3072 * 2);

  // weight prep (every call: ws is re-poisoned)
  convert_bf16<<<(768 * 768 + 255) / 256, 256, 0, stream>>>(conv_w, convwB, 768 * 768);
  transpose_w<<<dim3(2304 / 32, 768 / 32, 12), 256, 0, stream>>>(qkv_w, qkvT, 768, 2304);
  transpose_w<<<dim3(768 / 32, 768 / 32, 12), 256, 0, stream>>>(proj_w, projT, 768, 768);
  transpose_w<<<dim3(3072 / 32, 768 / 32, 12), 256, 0, stream>>>(fc1_w, fc1T, 768, 3072);
  transpose_w<<<dim3(768 / 32, 3072 / 32, 12), 256, 0, stream>>>(fc2_w, fc2T, 3072, 768);

  patch_extract<<<(6272 * 192) / 256, 256, 0, stream>>>(x, patches);
  h_init_full<<<(6304 * 192 + 255) / 256, 256, 0, stream>>>(cls, pos, h);
  gemm256<EPI_PATCH><<<dim3(25, 6, 4), 512, 0, stream>>>(
      patches, convwB, conv_b, nullptr, h, 6272, 768, 768, 192);

  for (int l = 0; l < 12; l++) {
    ln_bf16<<<1576, 256, 0, stream>>>(h, ln1_w + l * 768, ln1_b + l * 768, y, 6304);
    gemm256<EPI_BF16><<<dim3(25, 18, 1), 512, 0, stream>>>(
        y, qkvT + (size_t)l * 2304 * 768, qkv_b + l * 2304, qkvB, nullptr,
        6304, 2304, 768, 768);
    attn_kernel<<<32 * 12 * 4, 256, 0, stream>>>(qkvB, obuf);
    gemm256<EPI_RESID><<<dim3(25, 6, 4), 512, 0, stream>>>(
        obuf, projT + (size_t)l * 768 * 768, proj_b + l * 768, nullptr, h,
        6304, 768, 768, 192);
    ln_bf16<<<1576, 256, 0, stream>>>(h, ln2_w + l * 768, ln2_b + l * 768, y, 6304);
    gemm256<EPI_GELU><<<dim3(25, 24, 1), 512, 0, stream>>>(
        y, fc1T + (size_t)l * 3072 * 768, fc1_b + l * 3072, g, nullptr,
        6304, 3072, 768, 768);
    gemm256<EPI_RESID><<<dim3(25, 6, 4), 512, 0, stream>>>(
        g, fc2T + (size_t)l * 768 * 3072, fc2_b + l * 768, nullptr, h,
        6304, 768, 3072, 768);
  }
  ln_final<<<8, 256, 0, stream>>>(h, lnf_w, lnf_b, out);
}

// Round 7
// 3708.033 us; speedup vs baseline: 1.2407x; 1.2407x over previous
//
#include <hip/hip_runtime.h>
#include <cmath>

typedef __bf16 bf16;
typedef __bf16 bf16x8 __attribute__((ext_vector_type(8)));
typedef __bf16 bf16x4 __attribute__((ext_vector_type(4)));
typedef float  f32x4  __attribute__((ext_vector_type(4)));

#define MFMA16(a,b,c) __builtin_amdgcn_mfma_f32_16x16x32_bf16(a,b,c,0,0,0)

// async global->LDS, 16B per lane. LDS dest = wave-uniform base + lane*16.
__device__ __forceinline__ void async_ld16(const void* g, void* l) {
  __builtin_amdgcn_global_load_lds((__attribute__((address_space(1))) void*)(g),
                                   (__attribute__((address_space(3))) void*)(l),
                                   16, 0, 0);
}

enum { EPI_PATCH = 0, EPI_BF16 = 1, EPI_RESID = 2, EPI_GELU = 3 };

// -- 8-wave 128x128, RING-2 early-restage, T2 swizzle, SUPERTILE remap -------
// Evidence (r4-r6): throughput = resident blocks/CU x ~3 B/cy per block.
// Ring-2 = 32KB LDS -> 4 blocks/CU (wave-capped), vs ring-3's 3 (LDS-capped).
// K-step: barrier; ds_reads; lgkmcnt(0); barrier; stage(t+2); MFMA  -- the
// restage issues BEFORE the MFMA cluster (memory system fed earlier) and the
// post-MFMA barrier is gone. Counted vmcnt keeps stage t+1 in flight.
// Supertile: bijective XCD chunking + SB=5 bm-supergroups (bm_in fastest,
// zi slowest). REQUIRES gridDim.x % 5 == 0 (all call sites: nbm=50).
template <int EPI>
__global__ __launch_bounds__(512, 4) void gemm8(
    const bf16* __restrict__ A, const bf16* __restrict__ Wt,
    const float* __restrict__ bias, bf16* __restrict__ outB,
    float* __restrict__ outF, int M, int N, int K, int Kc)
{
  __shared__ bf16 As[2][128 * 32];                 // 16 KB
  __shared__ bf16 Bs[2][128 * 32];                 // 16 KB
  const int tid  = threadIdx.x;
  const int lane = tid & 63, wid = tid >> 6;       // wid 0..7
  const int qr   = lane & 15, quad = lane >> 4;
  const int wm   = wid >> 1, wn = wid & 1;         // wave tile 32x64

  // bijective XCD remap + supertile decode
  const int nbm = gridDim.x, nbn = gridDim.y, nz = gridDim.z;
  const int nwg = nbm * nbn * nz;
  const int orig = (blockIdx.z * nbn + blockIdx.y) * nbm + blockIdx.x;
  const int xcd = orig & 7, pos = orig >> 3;
  const int q8 = nwg >> 3, r8 = nwg & 7;
  const int w = (xcd < r8 ? xcd * (q8 + 1) : r8 * (q8 + 1) + (xcd - r8) * q8) + pos;
  constexpr int SB = 5;
  const int sgsz = SB * nbn * nz;
  const int sg = w / sgsz, rem = w % sgsz;
  const int bm = sg * SB + rem % SB;               // bm_in fastest
  const int bn = (rem / SB) % nbn;
  const int zi = rem / (SB * nbn);                 // zi slowest

  const int kbeg = zi * Kc;
  const int kend = min(K, kbeg + Kc);
  // staging: lane covers LDS row wid*16 + (lane>>2), slot lane&3 (linear).
  // Fetch the global column that belongs at this slot after the XOR swizzle.
  const int sr   = wid * 16 + (lane >> 2);         // staged row 0..127
  const int fst  = (lane >> 3) & 3;                // (row>>1)&3 for that row
  const int scol = (((lane & 3) ^ fst)) * 8;       // swizzled global col (elems)
  const int fr   = (qr >> 1) & 3;                  // (row>>1)&3 for read rows

  f32x4 zero4 = {0.f, 0.f, 0.f, 0.f};
  f32x4 acc[2][4];
#pragma unroll
  for (int i = 0; i < 2; i++)
#pragma unroll
    for (int j = 0; j < 4; j++) acc[i][j] = zero4;

  const int ra = min(bm * 128 + sr, M - 1);        // clamp ragged M
  const size_t nr = (size_t)(bn * 128 + sr);

  auto stage = [&](int buf, int k0) {   // 2 vmem ops / lane
    async_ld16(A  + (size_t)ra * K + k0 + scol, &As[buf][(wid * 16) * 32]);
    async_ld16(Wt + nr * K + k0 + scol,         &Bs[buf][(wid * 16) * 32]);
  };

  const int nt = (kend - kbeg) >> 5;               // >= 12 at every call site
  stage(0, kbeg); stage(1, kbeg + 32);
  int buf = 0;
  for (int t = 0; t < nt; ++t) {
    // wait until THIS step's stage is complete; keep stage t+1 in flight
    if (t + 1 < nt)  asm volatile("s_waitcnt vmcnt(2)" ::: "memory");
    else             asm volatile("s_waitcnt vmcnt(0)" ::: "memory");
    __builtin_amdgcn_s_barrier();                  // all waves' stage-t done
    asm volatile("" ::: "memory");
    bf16x8 af[2], bfr[4];
    const bf16* Ab = &As[buf][0];
    const bf16* Bb = &Bs[buf][0];
#pragma unroll
    for (int mi = 0; mi < 2; mi++)
      af[mi] = *(const bf16x8*)&Ab[(wm * 32 + mi * 16 + qr) * 32 + (quad ^ fr) * 8];
#pragma unroll
    for (int ni = 0; ni < 4; ni++)
      bfr[ni] = *(const bf16x8*)&Bb[(wn * 64 + ni * 16 + qr) * 32 + (quad ^ fr) * 8];
    asm volatile("s_waitcnt lgkmcnt(0)" ::: "memory");  // my reads retired
    __builtin_amdgcn_sched_barrier(0);             // rule #18 fence
    __builtin_amdgcn_s_barrier();                  // ALL waves' reads retired
    asm volatile("" ::: "memory");
    if (t + 2 < nt) stage(buf, kbeg + (t + 2) * 32);   // restage BEFORE MFMA
    __builtin_amdgcn_sched_barrier(0);             // pin stage above MFMA
    __builtin_amdgcn_s_setprio(1);
#pragma unroll
    for (int mi = 0; mi < 2; mi++)
#pragma unroll
      for (int ni = 0; ni < 4; ni++)
        acc[mi][ni] = MFMA16(af[mi], bfr[ni], acc[mi][ni]);
    __builtin_amdgcn_s_setprio(0);
    buf ^= 1;
  }

  // epilogue: C row = quad*4+r, col = lane&15 within each 16x16 tile
#pragma unroll
  for (int mi = 0; mi < 2; mi++) {
#pragma unroll
    for (int ni = 0; ni < 4; ni++) {
      const int row0 = bm * 128 + wm * 32 + mi * 16 + quad * 4;
      const int col  = bn * 128 + wn * 64 + ni * 16 + qr;
      const float bv = (zi == 0) ? bias[col] : 0.f;
#pragma unroll
      for (int r = 0; r < 4; r++) {
        const int row = row0 + r;
        if (row < M) {
          float v = acc[mi][ni][r] + bv;
          if constexpr (EPI == EPI_PATCH) {
            int bb = row / 196, nn = row % 196;
            int orow = bb * 197 + 1 + nn;
            atomicAdd(&outF[(size_t)orow * 768 + col], v);
          } else if constexpr (EPI == EPI_BF16) {
            outB[(size_t)row * N + col] = (bf16)v;
          } else if constexpr (EPI == EPI_GELU) {
            float gel = 0.5f * v * (1.f + erff(v * 0.70710678118f));
            outB[(size_t)row * N + col] = (bf16)gel;
          } else {  // EPI_RESID: h += (acc + bias)
            atomicAdd(&outF[(size_t)row * 768 + col], v);
          }
        }
      }
    }
  }
}

// Attention: one block = (b, head, 64 q-rows). Full K/V in LDS. S=197, dh=64.
// P aliases K's LDS (K dead after scores) -> 67 KB -> 2 blocks/CU.
__global__ __launch_bounds__(256) void attn_kernel(
    const bf16* __restrict__ qkv, bf16* __restrict__ o)
{
  __shared__ __align__(16) char smem[68864];
  bf16 (*Qs)[72]  = (bf16(*)[72])(smem);                 //  9216 B
  bf16 (*Ks)[72]  = (bf16(*)[72])(smem + 9216);          // 29952 B
  bf16 (*Ps)[232] = (bf16(*)[232])(smem + 9216);         // aliases Ks (29696 B)
  bf16 (*Vt)[232] = (bf16(*)[232])(smem + 39168);        // 29696 B

  const int tid  = threadIdx.x;
  const int lane = tid & 63, wid = tid >> 6;
  const int qr   = lane & 15, quad = lane >> 4;
  const int qt   = blockIdx.x & 3, bh = blockIdx.x >> 2;
  const int head = bh % 12, b = bh / 12;
  const int q0   = qt * 64;
  const size_t base = (size_t)b * 197 * 2304 + head * 64;

  // stage Q (clamp rows >196 to 196; garbage rows never stored)
  {
    int r = tid >> 2, cb = (tid & 3) * 16;
    int s = q0 + r; if (s > 196) s = 196;
    const bf16* src = qkv + base + (size_t)s * 2304 + cb;
    *(uint4*)&Qs[r][cb]     = *(const uint4*)src;
    *(uint4*)&Qs[r][cb + 8] = *(const uint4*)(src + 8);
  }
  // stage K rows 0..207 (zeros >=197)
  for (int rr = tid >> 2; rr < 208; rr += 64) {
    int cb = (tid & 3) * 16;
    uint4 v0 = make_uint4(0, 0, 0, 0), v1 = make_uint4(0, 0, 0, 0);
    if (rr < 197) {
      const bf16* src = qkv + base + 768 + (size_t)rr * 2304 + cb;
      v0 = *(const uint4*)src; v1 = *(const uint4*)(src + 8);
    }
    *(uint4*)&Ks[rr][cb] = v0; *(uint4*)&Ks[rr][cb + 8] = v1;
  }
  // stage V transposed [d][key] (zeros for key>=197)
  for (int rr = tid >> 2; rr < 224; rr += 64) {
    int cb = (tid & 3) * 16;
    bf16 tmp[16];
    if (rr < 197) {
      const bf16* src = qkv + base + 1536 + (size_t)rr * 2304 + cb;
      *(uint4*)&tmp[0] = *(const uint4*)src;
      *(uint4*)&tmp[8] = *(const uint4*)(src + 8);
    } else {
#pragma unroll
      for (int j = 0; j < 16; j++) tmp[j] = (bf16)0.f;
    }
#pragma unroll
    for (int j = 0; j < 16; j++) Vt[cb + j][rr] = tmp[j];
  }
  __syncthreads();

  // scores: wave handles q rows [wid*16, wid*16+16)
  bf16x8 qa0 = *(const bf16x8*)&Qs[wid * 16 + qr][quad * 8];
  bf16x8 qa1 = *(const bf16x8*)&Qs[wid * 16 + qr][32 + quad * 8];
  f32x4 zero4 = {0.f, 0.f, 0.f, 0.f};
  f32x4 sc[13];
#pragma unroll
  for (int t = 0; t < 13; t++) sc[t] = zero4;
#pragma unroll
  for (int t = 0; t < 13; t++) {
    bf16x8 kb0 = *(const bf16x8*)&Ks[t * 16 + qr][quad * 8];
    bf16x8 kb1 = *(const bf16x8*)&Ks[t * 16 + qr][32 + quad * 8];
    sc[t] = MFMA16(qa0, kb0, sc[t]);
    sc[t] = MFMA16(qa1, kb1, sc[t]);
  }
  // softmax: lane holds col=16t+qr, row=quad*4+r; row-reduce across 16 lanes
  float mx[4] = {-1e30f, -1e30f, -1e30f, -1e30f};
#pragma unroll
  for (int t = 0; t < 13; t++) {
    bool valid = (t * 16 + qr) < 197;
#pragma unroll
    for (int r = 0; r < 4; r++) {
      float v = sc[t][r] * 0.125f;
      sc[t][r] = v;
      if (valid) mx[r] = fmaxf(mx[r], v);
    }
  }
#pragma unroll
  for (int r = 0; r < 4; r++)
#pragma unroll
    for (int off = 1; off < 16; off <<= 1)
      mx[r] = fmaxf(mx[r], __shfl_xor(mx[r], off, 16));
  float sum[4] = {0.f, 0.f, 0.f, 0.f};
#pragma unroll
  for (int t = 0; t < 13; t++) {
    bool valid = (t * 16 + qr) < 197;
#pragma unroll
    for (int r = 0; r < 4; r++) {
      float e = valid ? __expf(sc[t][r] - mx[r]) : 0.f;
      sc[t][r] = e; sum[r] += e;
    }
  }
#pragma unroll
  for (int r = 0; r < 4; r++) {
#pragma unroll
    for (int off = 1; off < 16; off <<= 1)
      sum[r] += __shfl_xor(sum[r], off, 16);
    sum[r] = 1.f / sum[r];
  }
  __syncthreads();   // all waves done reading Ks; safe to overwrite with Ps
#pragma unroll
  for (int t = 0; t < 13; t++)
#pragma unroll
    for (int r = 0; r < 4; r++)
      Ps[wid * 16 + quad * 4 + r][t * 16 + qr] = (bf16)(sc[t][r] * sum[r]);
  // zero Ps pad cols [208,224): wave covers its own 16 rows
  {
    bf16x4 zz = {(bf16)0.f, (bf16)0.f, (bf16)0.f, (bf16)0.f};
    *(bf16x4*)&Ps[wid * 16 + qr][208 + quad * 4] = zz;
  }
  __syncthreads();

  // PV: O[64 x 64] per wave-tile; K-loop over padded 224 keys
  f32x4 oa[4];
#pragma unroll
  for (int ni = 0; ni < 4; ni++) oa[ni] = zero4;
#pragma unroll
  for (int k0 = 0; k0 < 224; k0 += 32) {
    bf16x8 pa = *(const bf16x8*)&Ps[wid * 16 + qr][k0 + quad * 8];
#pragma unroll
    for (int ni = 0; ni < 4; ni++) {
      bf16x8 vb = *(const bf16x8*)&Vt[ni * 16 + qr][k0 + quad * 8];
      oa[ni] = MFMA16(pa, vb, oa[ni]);
    }
  }
  // store O at [b][s][head][d]
#pragma unroll
  for (int ni = 0; ni < 4; ni++)
#pragma unroll
    for (int r = 0; r < 4; r++) {
      int row = q0 + wid * 16 + quad * 4 + r;
      if (row < 197)
        o[(((size_t)b * 197 + row) * 12 + head) * 64 + ni * 16 + qr] =
            (bf16)oa[ni][r];
    }
}

// LayerNorm over 768, one wave per row, bf16 out
__global__ __launch_bounds__(256) void ln_bf16(
    const float* __restrict__ h, const float* __restrict__ w,
    const float* __restrict__ b, bf16* __restrict__ y, int rows)
{
  int row = blockIdx.x * 4 + (threadIdx.x >> 6);
  int lane = threadIdx.x & 63;
  if (row >= rows) return;
  const float* hr = h + (size_t)row * 768;
  float v[12]; float s = 0.f;
#pragma unroll
  for (int i = 0; i < 12; i++) { v[i] = hr[lane + 64 * i]; s += v[i]; }
#pragma unroll
  for (int off = 32; off >= 1; off >>= 1) s += __shfl_xor(s, off, 64);
  float mean = s * (1.f / 768.f);
  float q = 0.f;
#pragma unroll
  for (int i = 0; i < 12; i++) { float d = v[i] - mean; q += d * d; }
#pragma unroll
  for (int off = 32; off >= 1; off >>= 1) q += __shfl_xor(q, off, 64);
  float rstd = rsqrtf(q * (1.f / 768.f) + 1e-6f);
  bf16* yr = y + (size_t)row * 768;
#pragma unroll
  for (int i = 0; i < 12; i++)
    yr[lane + 64 * i] = (bf16)((v[i] - mean) * rstd * w[lane + 64 * i] + b[lane + 64 * i]);
}

// Final LN on the 32 CLS rows, fp32 out
__global__ __launch_bounds__(256) void ln_final(
    const float* __restrict__ h, const float* __restrict__ w,
    const float* __restrict__ b, float* __restrict__ out)
{
  int bi = blockIdx.x * 4 + (threadIdx.x >> 6);
  int lane = threadIdx.x & 63;
  if (bi >= 32) return;
  const float* hr = h + (size_t)bi * 197 * 768;
  float v[12]; float s = 0.f;
#pragma unroll
  for (int i = 0; i < 12; i++) { v[i] = hr[lane + 64 * i]; s += v[i]; }
#pragma unroll
  for (int off = 32; off >= 1; off >>= 1) s += __shfl_xor(s, off, 64);
  float mean = s * (1.f / 768.f);
  float q = 0.f;
#pragma unroll
  for (int i = 0; i < 12; i++) { float d = v[i] - mean; q += d * d; }
#pragma unroll
  for (int off = 32; off >= 1; off >>= 1) q += __shfl_xor(q, off, 64);
  float rstd = rsqrtf(q * (1.f / 768.f) + 1e-6f);
#pragma unroll
  for (int i = 0; i < 12; i++)
    out[(size_t)bi * 768 + lane + 64 * i] =
        (v[i] - mean) * rstd * w[lane + 64 * i] + b[lane + 64 * i];
}

// [z][R][C] fp32 -> [z][C][R] bf16 (all dims multiples of 32)
__global__ __launch_bounds__(256) void transpose_w(
    const float* __restrict__ in, bf16* __restrict__ out, int R, int C)
{
  __shared__ float t[32][33];
  size_t zoff = (size_t)blockIdx.z * R * C;
  in += zoff; out += zoff;
  int c0 = blockIdx.x * 32, r0 = blockIdx.y * 32;
  int lx = threadIdx.x & 31, ly = threadIdx.x >> 5;  // 32 x 8
#pragma unroll
  for (int i = 0; i < 32; i += 8) t[ly + i][lx] = in[(size_t)(r0 + ly + i) * C + c0 + lx];
  __syncthreads();
#pragma unroll
  for (int i = 0; i < 32; i += 8)
    out[(size_t)(c0 + ly + i) * R + r0 + lx] = (bf16)t[lx][ly + i];
}

__global__ __launch_bounds__(256) void convert_bf16(
    const float* __restrict__ in, bf16* __restrict__ out, int n)
{
  int i = blockIdx.x * 256 + threadIdx.x;
  if (i < n) out[i] = (bf16)in[i];
}

// x(32,3,224,224) -> patches[6272][768] bf16; k = c*256 + iy*16 + ix
__global__ __launch_bounds__(256) void patch_extract(
    const float* __restrict__ x, bf16* __restrict__ patches)
{
  int i = blockIdx.x * 256 + threadIdx.x;
  if (i >= 6272 * 192) return;
  int m = i / 192, kq = (i % 192) * 4;
  int b = m / 196, pp = m % 196, py = pp / 14, px = pp % 14;
  int c = kq >> 8, rem = kq & 255, iy = rem >> 4, ix = rem & 15;
  const float4 v = *(const float4*)&x[(((size_t)(b * 3 + c) * 224 + py * 16 + iy) * 224) + px * 16 + ix];
  bf16x4 pv = {(bf16)v.x, (bf16)v.y, (bf16)v.z, (bf16)v.w};
  *(bf16x4*)&patches[(size_t)m * 768 + kq] = pv;
}

// prefill h: h[b][s][:] = pos[s] (+ cls for s==0); patch GEMM then accumulates
__global__ __launch_bounds__(256) void h_init_full(
    const float* __restrict__ cls, const float* __restrict__ pos,
    float* __restrict__ h)
{
  int i = blockIdx.x * 256 + threadIdx.x;
  if (i >= 6304 * 192) return;
  int row = i / 192, c4 = (i % 192) * 4;
  int s = row % 197;
  float4 pv = *(const float4*)&pos[(size_t)s * 768 + c4];
  if (s == 0) {
    float4 cv = *(const float4*)&cls[c4];
    pv.x += cv.x; pv.y += cv.y; pv.z += cv.z; pv.w += cv.w;
  }
  *(float4*)&h[(size_t)row * 768 + c4] = pv;
}

extern "C" void kernel_launch(void* const* d_in, const int* in_sizes, int n_in,
                              void* d_out, int out_size, void* d_ws, size_t ws_size,
                              hipStream_t stream)
{
  const float* x      = (const float*)d_in[0];
  const float* conv_w = (const float*)d_in[1];
  const float* conv_b = (const float*)d_in[2];
  const float* cls    = (const float*)d_in[3];
  const float* pos    = (const float*)d_in[4];
  const float* ln1_w  = (const float*)d_in[5];
  const float* ln1_b  = (const float*)d_in[6];
  const float* qkv_w  = (const float*)d_in[7];
  const float* qkv_b  = (const float*)d_in[8];
  const float* proj_w = (const float*)d_in[9];
  const float* proj_b = (const float*)d_in[10];
  const float* ln2_w  = (const float*)d_in[11];
  const float* ln2_b  = (const float*)d_in[12];
  const float* fc1_w  = (const float*)d_in[13];
  const float* fc1_b  = (const float*)d_in[14];
  const float* fc2_w  = (const float*)d_in[15];
  const float* fc2_b  = (const float*)d_in[16];
  const float* lnf_w  = (const float*)d_in[17];
  const float* lnf_b  = (const float*)d_in[18];
  float* out = (float*)d_out;
  (void)in_sizes; (void)n_in; (void)out_size; (void)ws_size;

  char* ws = (char*)d_ws;
  size_t off = 0;
  auto alloc = [&](size_t bytes) -> char* {
    char* p = ws + off;
    off += (bytes + 255) & ~(size_t)255;
    return p;
  };

  bf16*  convwB  = (bf16*)alloc((size_t)768 * 768 * 2);
  bf16*  qkvT    = (bf16*)alloc((size_t)12 * 2304 * 768 * 2);
  bf16*  projT   = (bf16*)alloc((size_t)12 * 768 * 768 * 2);
  bf16*  fc1T    = (bf16*)alloc((size_t)12 * 3072 * 768 * 2);
  bf16*  fc2T    = (bf16*)alloc((size_t)12 * 768 * 3072 * 2);
  bf16*  patches = (bf16*)alloc((size_t)6272 * 768 * 2);
  float* h       = (float*)alloc((size_t)6304 * 768 * 4);
  bf16*  y       = (bf16*)alloc((size_t)6304 * 768 * 2);
  bf16*  qkvB    = (bf16*)alloc((size_t)6304 * 2304 * 2);
  bf16*  obuf    = (bf16*)alloc((size_t)6304 * 768 * 2);
  bf16*  g       = (bf16*)alloc((size_t)6304 * 3072 * 2);

  // weight prep (every call: ws is re-poisoned)
  convert_bf16<<<(768 * 768 + 255) / 256, 256, 0, stream>>>(conv_w, convwB, 768 * 768);
  transpose_w<<<dim3(2304 / 32, 768 / 32, 12), 256, 0, stream>>>(qkv_w, qkvT, 768, 2304);
  transpose_w<<<dim3(768 / 32, 768 / 32, 12), 256, 0, stream>>>(proj_w, projT, 768, 768);
  transpose_w<<<dim3(3072 / 32, 768 / 32, 12), 256, 0, stream>>>(fc1_w, fc1T, 768, 3072);
  transpose_w<<<dim3(768 / 32, 3072 / 32, 12), 256, 0, stream>>>(fc2_w, fc2T, 3072, 768);

  patch_extract<<<(6272 * 192) / 256, 256, 0, stream>>>(x, patches);
  h_init_full<<<(6304 * 192 + 255) / 256, 256, 0, stream>>>(cls, pos, h);
  gemm8<EPI_PATCH><<<dim3(50, 6, 2), 512, 0, stream>>>(
      patches, convwB, conv_b, nullptr, h, 6272, 768, 768, 384);

  for (int l = 0; l < 12; l++) {
    ln_bf16<<<1576, 256, 0, stream>>>(h, ln1_w + l * 768, ln1_b + l * 768, y, 6304);
    gemm8<EPI_BF16><<<dim3(50, 18, 1), 512, 0, stream>>>(
        y, qkvT + (size_t)l * 2304 * 768, qkv_b + l * 2304, qkvB, nullptr,
        6304, 2304, 768, 768);
    attn_kernel<<<32 * 12 * 4, 256, 0, stream>>>(qkvB, obuf);
    gemm8<EPI_RESID><<<dim3(50, 6, 2), 512, 0, stream>>>(
        obuf, projT + (size_t)l * 768 * 768, proj_b + l * 768, nullptr, h,
        6304, 768, 768, 384);
    ln_bf16<<<1576, 256, 0, stream>>>(h, ln2_w + l * 768, ln2_b + l * 768, y, 6304);
    gemm8<EPI_GELU><<<dim3(50, 24, 1), 512, 0, stream>>>(
        y, fc1T + (size_t)l * 3072 * 768, fc1_b + l * 3072, g, nullptr,
        6304, 3072, 768, 768);
    gemm8<EPI_RESID><<<dim3(50, 6, 4), 512, 0, stream>>>(
        g, fc2T + (size_t)l * 768 * 3072, fc2_b + l * 768, nullptr, h,
        6304, 768, 3072, 768);
  }
  ln_final<<<8, 256, 0, stream>>>(h, lnf_w, lnf_b, out);
}

// Round 8
// 3401.623 us; speedup vs baseline: 1.3525x; 1.0901x over previous
//
#include <hip/hip_runtime.h>
#include <cmath>

typedef __bf16 bf16;
typedef __bf16 bf16x8 __attribute__((ext_vector_type(8)));
typedef __bf16 bf16x4 __attribute__((ext_vector_type(4)));
typedef float  f32x4  __attribute__((ext_vector_type(4)));

#define MFMA16(a,b,c) __builtin_amdgcn_mfma_f32_16x16x32_bf16(a,b,c,0,0,0)

// async global->LDS, 16B per lane. LDS dest = wave-uniform base + lane*16.
__device__ __forceinline__ void async_ld16(const void* g, void* l) {
  __builtin_amdgcn_global_load_lds((__attribute__((address_space(1))) void*)(g),
                                   (__attribute__((address_space(3))) void*)(l),
                                   16, 0, 0);
}

enum { EPI_PATCH = 0, EPI_BF16 = 1, EPI_RESID = 2, EPI_GELU = 3 };

// ---- 8-wave 128x128, ring-3 counted-vmcnt, T2 swizzle, SUPERTILE remap -----
// Round-5 proven config (3418us): bijective XCD chunking (m204) + SB=5 bm
// supergroups (bm_in fastest) -> 5 concurrent blocks share one weight panel
// (L3 merge) and their A-panels stay L2-resident across the bn sweep; zi
// slowest separates split-K atomic slices. fc2 z=2 ONLY (z=4 regressed r7:
// cross-XCD atomic RMW contention). REQUIRES gridDim.x % 5 == 0 (nbm=50).
template <int EPI>
__global__ __launch_bounds__(512, 4) void gemm8(
    const bf16* __restrict__ A, const bf16* __restrict__ Wt,
    const float* __restrict__ bias, bf16* __restrict__ outB,
    float* __restrict__ outF, int M, int N, int K, int Kc)
{
  __shared__ bf16 As[3][128 * 32];
  __shared__ bf16 Bs[3][128 * 32];
  const int tid  = threadIdx.x;
  const int lane = tid & 63, wid = tid >> 6;       // wid 0..7
  const int qr   = lane & 15, quad = lane >> 4;
  const int wm   = wid >> 1, wn = wid & 1;         // wave tile 32x64

  // bijective XCD remap + supertile decode
  const int nbm = gridDim.x, nbn = gridDim.y, nz = gridDim.z;
  const int nwg = nbm * nbn * nz;
  const int orig = (blockIdx.z * nbn + blockIdx.y) * nbm + blockIdx.x;
  const int xcd = orig & 7, pos = orig >> 3;
  const int q8 = nwg >> 3, r8 = nwg & 7;
  const int w = (xcd < r8 ? xcd * (q8 + 1) : r8 * (q8 + 1) + (xcd - r8) * q8) + pos;
  constexpr int SB = 5;
  const int sgsz = SB * nbn * nz;
  const int sg = w / sgsz, rem = w % sgsz;
  const int bm = sg * SB + rem % SB;               // bm_in fastest
  const int bn = (rem / SB) % nbn;
  const int zi = rem / (SB * nbn);                 // zi slowest

  const int kbeg = zi * Kc;
  const int kend = min(K, kbeg + Kc);
  // staging: lane covers LDS row wid*16 + (lane>>2), slot lane&3 (linear).
  // Fetch the global column that belongs at this slot after the XOR swizzle.
  const int sr   = wid * 16 + (lane >> 2);         // staged row 0..127
  const int fst  = (lane >> 3) & 3;                // (row>>1)&3 for that row
  const int scol = (((lane & 3) ^ fst)) * 8;       // swizzled global col (elems)
  const int fr   = (qr >> 1) & 3;                  // (row>>1)&3 for read rows

  f32x4 zero4 = {0.f, 0.f, 0.f, 0.f};
  f32x4 acc[2][4];
#pragma unroll
  for (int i = 0; i < 2; i++)
#pragma unroll
    for (int j = 0; j < 4; j++) acc[i][j] = zero4;

  const int ra = min(bm * 128 + sr, M - 1);        // clamp ragged M
  const size_t nr = (size_t)(bn * 128 + sr);

  auto stage = [&](int buf, int k0) {   // 2 vmem ops / lane
    async_ld16(A  + (size_t)ra * K + k0 + scol, &As[buf][(wid * 16) * 32]);
    async_ld16(Wt + nr * K + k0 + scol,         &Bs[buf][(wid * 16) * 32]);
  };

  const int nt = (kend - kbeg) >> 5;               // >= 12 at every call site
  stage(0, kbeg); stage(1, kbeg + 32); stage(2, kbeg + 64);
  int buf = 0;
  for (int t = 0; t < nt; ++t) {
    // wait until THIS step's stage is complete; keep later stages in flight
    if (t + 2 < nt)       asm volatile("s_waitcnt vmcnt(4)" ::: "memory");
    else if (t + 1 < nt)  asm volatile("s_waitcnt vmcnt(2)" ::: "memory");
    else                  asm volatile("s_waitcnt vmcnt(0)" ::: "memory");
    __builtin_amdgcn_s_barrier();                  // all waves' stage-t done
    asm volatile("" ::: "memory");
    bf16x8 af[2], bfr[4];
    const bf16* Ab = &As[buf][0];
    const bf16* Bb = &Bs[buf][0];
#pragma unroll
    for (int mi = 0; mi < 2; mi++)
      af[mi] = *(const bf16x8*)&Ab[(wm * 32 + mi * 16 + qr) * 32 + (quad ^ fr) * 8];
#pragma unroll
    for (int ni = 0; ni < 4; ni++)
      bfr[ni] = *(const bf16x8*)&Bb[(wn * 64 + ni * 16 + qr) * 32 + (quad ^ fr) * 8];
    __builtin_amdgcn_s_setprio(1);
#pragma unroll
    for (int mi = 0; mi < 2; mi++)
#pragma unroll
      for (int ni = 0; ni < 4; ni++)
        acc[mi][ni] = MFMA16(af[mi], bfr[ni], acc[mi][ni]);
    __builtin_amdgcn_s_setprio(0);
    __builtin_amdgcn_sched_barrier(0);             // pin reads+MFMA before reuse
    asm volatile("" ::: "memory");
    __builtin_amdgcn_s_barrier();                  // all waves done reading buf
    asm volatile("" ::: "memory");
    if (t + 3 < nt) stage(buf, kbeg + (t + 3) * 32);
    buf = (buf == 2) ? 0 : buf + 1;
  }

  // epilogue: C row = quad*4+r, col = lane&15 within each 16x16 tile
#pragma unroll
  for (int mi = 0; mi < 2; mi++) {
#pragma unroll
    for (int ni = 0; ni < 4; ni++) {
      const int row0 = bm * 128 + wm * 32 + mi * 16 + quad * 4;
      const int col  = bn * 128 + wn * 64 + ni * 16 + qr;
      const float bv = (zi == 0) ? bias[col] : 0.f;
#pragma unroll
      for (int r = 0; r < 4; r++) {
        const int row = row0 + r;
        if (row < M) {
          float v = acc[mi][ni][r] + bv;
          if constexpr (EPI == EPI_PATCH) {
            int bb = row / 196, nn = row % 196;
            int orow = bb * 197 + 1 + nn;
            atomicAdd(&outF[(size_t)orow * 768 + col], v);
          } else if constexpr (EPI == EPI_BF16) {
            outB[(size_t)row * N + col] = (bf16)v;
          } else if constexpr (EPI == EPI_GELU) {
            float gel = 0.5f * v * (1.f + erff(v * 0.70710678118f));
            outB[(size_t)row * N + col] = (bf16)gel;
          } else {  // EPI_RESID: h += (acc + bias)
            atomicAdd(&outF[(size_t)row * 768 + col], v);
          }
        }
      }
    }
  }
}

// Attention: one block = (b, head, 64 q-rows). K/V in LDS; Q DIRECT TO REGS
// (each lane loads exactly its MFMA A-fragment: 2x bf16x8). LDS 59.6 KB.
__global__ __launch_bounds__(256) void attn_kernel(
    const bf16* __restrict__ qkv, bf16* __restrict__ o)
{
  __shared__ __align__(16) char smem[59648];
  bf16 (*Ks)[72]  = (bf16(*)[72])(smem);                 // 29952 B
  bf16 (*Ps)[232] = (bf16(*)[232])(smem);                // aliases Ks (29696 B)
  bf16 (*Vt)[232] = (bf16(*)[232])(smem + 29952);        // 29696 B

  const int tid  = threadIdx.x;
  const int lane = tid & 63, wid = tid >> 6;
  const int qr   = lane & 15, quad = lane >> 4;
  const int qt   = blockIdx.x & 3, bh = blockIdx.x >> 2;
  const int head = bh % 12, b = bh / 12;
  const int q0   = qt * 64;
  const size_t base = (size_t)b * 197 * 2304 + head * 64;

  // Q fragment direct from global (clamp rows >196; garbage never stored)
  int qrow = q0 + wid * 16 + qr; if (qrow > 196) qrow = 196;
  const bf16* qsrc = qkv + base + (size_t)qrow * 2304;
  bf16x8 qa0 = *(const bf16x8*)(qsrc + quad * 8);
  bf16x8 qa1 = *(const bf16x8*)(qsrc + 32 + quad * 8);

  // stage K rows 0..207 (zeros >=197)
  for (int rr = tid >> 2; rr < 208; rr += 64) {
    int cb = (tid & 3) * 16;
    uint4 v0 = make_uint4(0, 0, 0, 0), v1 = make_uint4(0, 0, 0, 0);
    if (rr < 197) {
      const bf16* src = qkv + base + 768 + (size_t)rr * 2304 + cb;
      v0 = *(const uint4*)src; v1 = *(const uint4*)(src + 8);
    }
    *(uint4*)&Ks[rr][cb] = v0; *(uint4*)&Ks[rr][cb + 8] = v1;
  }
  // stage V transposed [d][key] (zeros for key>=197)
  for (int rr = tid >> 2; rr < 224; rr += 64) {
    int cb = (tid & 3) * 16;
    bf16 tmp[16];
    if (rr < 197) {
      const bf16* src = qkv + base + 1536 + (size_t)rr * 2304 + cb;
      *(uint4*)&tmp[0] = *(const uint4*)src;
      *(uint4*)&tmp[8] = *(const uint4*)(src + 8);
    } else {
#pragma unroll
      for (int j = 0; j < 16; j++) tmp[j] = (bf16)0.f;
    }
#pragma unroll
    for (int j = 0; j < 16; j++) Vt[cb + j][rr] = tmp[j];
  }
  __syncthreads();

  // scores: wave handles q rows [wid*16, wid*16+16)
  f32x4 zero4 = {0.f, 0.f, 0.f, 0.f};
  f32x4 sc[13];
#pragma unroll
  for (int t = 0; t < 13; t++) sc[t] = zero4;
#pragma unroll
  for (int t = 0; t < 13; t++) {
    bf16x8 kb0 = *(const bf16x8*)&Ks[t * 16 + qr][quad * 8];
    bf16x8 kb1 = *(const bf16x8*)&Ks[t * 16 + qr][32 + quad * 8];
    sc[t] = MFMA16(qa0, kb0, sc[t]);
    sc[t] = MFMA16(qa1, kb1, sc[t]);
  }
  // softmax: lane holds col=16t+qr, row=quad*4+r; row-reduce across 16 lanes
  float mx[4] = {-1e30f, -1e30f, -1e30f, -1e30f};
#pragma unroll
  for (int t = 0; t < 13; t++) {
    bool valid = (t * 16 + qr) < 197;
#pragma unroll
    for (int r = 0; r < 4; r++) {
      float v = sc[t][r] * 0.125f;
      sc[t][r] = v;
      if (valid) mx[r] = fmaxf(mx[r], v);
    }
  }
#pragma unroll
  for (int r = 0; r < 4; r++)
#pragma unroll
    for (int off = 1; off < 16; off <<= 1)
      mx[r] = fmaxf(mx[r], __shfl_xor(mx[r], off, 16));
  float sum[4] = {0.f, 0.f, 0.f, 0.f};
#pragma unroll
  for (int t = 0; t < 13; t++) {
    bool valid = (t * 16 + qr) < 197;
#pragma unroll
    for (int r = 0; r < 4; r++) {
      float e = valid ? __expf(sc[t][r] - mx[r]) : 0.f;
      sc[t][r] = e; sum[r] += e;
    }
  }
#pragma unroll
  for (int r = 0; r < 4; r++) {
#pragma unroll
    for (int off = 1; off < 16; off <<= 1)
      sum[r] += __shfl_xor(sum[r], off, 16);
    sum[r] = 1.f / sum[r];
  }
  __syncthreads();   // all waves done reading Ks; safe to overwrite with Ps
#pragma unroll
  for (int t = 0; t < 13; t++)
#pragma unroll
    for (int r = 0; r < 4; r++)
      Ps[wid * 16 + quad * 4 + r][t * 16 + qr] = (bf16)(sc[t][r] * sum[r]);
  // zero Ps pad cols [208,224): wave covers its own 16 rows
  {
    bf16x4 zz = {(bf16)0.f, (bf16)0.f, (bf16)0.f, (bf16)0.f};
    *(bf16x4*)&Ps[wid * 16 + qr][208 + quad * 4] = zz;
  }
  __syncthreads();

  // PV: O[64 x 64] per wave-tile; K-loop over padded 224 keys
  f32x4 oa[4];
#pragma unroll
  for (int ni = 0; ni < 4; ni++) oa[ni] = zero4;
#pragma unroll
  for (int k0 = 0; k0 < 224; k0 += 32) {
    bf16x8 pa = *(const bf16x8*)&Ps[wid * 16 + qr][k0 + quad * 8];
#pragma unroll
    for (int ni = 0; ni < 4; ni++) {
      bf16x8 vb = *(const bf16x8*)&Vt[ni * 16 + qr][k0 + quad * 8];
      oa[ni] = MFMA16(pa, vb, oa[ni]);
    }
  }
  // store O at [b][s][head][d]
#pragma unroll
  for (int ni = 0; ni < 4; ni++)
#pragma unroll
    for (int r = 0; r < 4; r++) {
      int row = q0 + wid * 16 + quad * 4 + r;
      if (row < 197)
        o[(((size_t)b * 197 + row) * 12 + head) * 64 + ni * 16 + qr] =
            (bf16)oa[ni][r];
    }
}

// LayerNorm over 768, one wave per row, bf16 out. float4 loads (G13).
__global__ __launch_bounds__(256) void ln_bf16(
    const float* __restrict__ h, const float* __restrict__ w,
    const float* __restrict__ b, bf16* __restrict__ y, int rows)
{
  int row = blockIdx.x * 4 + (threadIdx.x >> 6);
  int lane = threadIdx.x & 63;
  if (row >= rows) return;
  const float* hr = h + (size_t)row * 768;
  f32x4 v[3]; float s = 0.f;
#pragma unroll
  for (int j = 0; j < 3; j++) {
    v[j] = *(const f32x4*)&hr[lane * 4 + 256 * j];
#pragma unroll
    for (int e = 0; e < 4; e++) s += v[j][e];
  }
#pragma unroll
  for (int off = 32; off >= 1; off >>= 1) s += __shfl_xor(s, off, 64);
  float mean = s * (1.f / 768.f);
  float q = 0.f;
#pragma unroll
  for (int j = 0; j < 3; j++)
#pragma unroll
    for (int e = 0; e < 4; e++) { float d = v[j][e] - mean; q += d * d; }
#pragma unroll
  for (int off = 32; off >= 1; off >>= 1) q += __shfl_xor(q, off, 64);
  float rstd = rsqrtf(q * (1.f / 768.f) + 1e-6f);
  bf16* yr = y + (size_t)row * 768;
#pragma unroll
  for (int j = 0; j < 3; j++) {
    int col = lane * 4 + 256 * j;
    f32x4 wv = *(const f32x4*)&w[col];
    f32x4 bv = *(const f32x4*)&b[col];
    bf16x4 ov;
#pragma unroll
    for (int e = 0; e < 4; e++)
      ov[e] = (bf16)((v[j][e] - mean) * rstd * wv[e] + bv[e]);
    *(bf16x4*)&yr[col] = ov;
  }
}

// Final LN on the 32 CLS rows, fp32 out. float4 loads.
__global__ __launch_bounds__(256) void ln_final(
    const float* __restrict__ h, const float* __restrict__ w,
    const float* __restrict__ b, float* __restrict__ out)
{
  int bi = blockIdx.x * 4 + (threadIdx.x >> 6);
  int lane = threadIdx.x & 63;
  if (bi >= 32) return;
  const float* hr = h + (size_t)bi * 197 * 768;
  f32x4 v[3]; float s = 0.f;
#pragma unroll
  for (int j = 0; j < 3; j++) {
    v[j] = *(const f32x4*)&hr[lane * 4 + 256 * j];
#pragma unroll
    for (int e = 0; e < 4; e++) s += v[j][e];
  }
#pragma unroll
  for (int off = 32; off >= 1; off >>= 1) s += __shfl_xor(s, off, 64);
  float mean = s * (1.f / 768.f);
  float q = 0.f;
#pragma unroll
  for (int j = 0; j < 3; j++)
#pragma unroll
    for (int e = 0; e < 4; e++) { float d = v[j][e] - mean; q += d * d; }
#pragma unroll
  for (int off = 32; off >= 1; off >>= 1) q += __shfl_xor(q, off, 64);
  float rstd = rsqrtf(q * (1.f / 768.f) + 1e-6f);
#pragma unroll
  for (int j = 0; j < 3; j++) {
    int col = lane * 4 + 256 * j;
    f32x4 wv = *(const f32x4*)&w[col];
    f32x4 bv = *(const f32x4*)&b[col];
    f32x4 ov;
#pragma unroll
    for (int e = 0; e < 4; e++)
      ov[e] = (v[j][e] - mean) * rstd * wv[e] + bv[e];
    *(f32x4*)&out[(size_t)bi * 768 + col] = ov;
  }
}

// [z][R][C] fp32 -> [z][C][R] bf16 (all dims multiples of 32)
__global__ __launch_bounds__(256) void transpose_w(
    const float* __restrict__ in, bf16* __restrict__ out, int R, int C)
{
  __shared__ float t[32][33];
  size_t zoff = (size_t)blockIdx.z * R * C;
  in += zoff; out += zoff;
  int c0 = blockIdx.x * 32, r0 = blockIdx.y * 32;
  int lx = threadIdx.x & 31, ly = threadIdx.x >> 5;  // 32 x 8
#pragma unroll
  for (int i = 0; i < 32; i += 8) t[ly + i][lx] = in[(size_t)(r0 + ly + i) * C + c0 + lx];
  __syncthreads();
#pragma unroll
  for (int i = 0; i < 32; i += 8)
    out[(size_t)(c0 + ly + i) * R + r0 + lx] = (bf16)t[lx][ly + i];
}

__global__ __launch_bounds__(256) void convert_bf16(
    const float* __restrict__ in, bf16* __restrict__ out, int n)
{
  int i = blockIdx.x * 256 + threadIdx.x;
  if (i < n) out[i] = (bf16)in[i];
}

// x(32,3,224,224) -> patches[6272][768] bf16; k = c*256 + iy*16 + ix
__global__ __launch_bounds__(256) void patch_extract(
    const float* __restrict__ x, bf16* __restrict__ patches)
{
  int i = blockIdx.x * 256 + threadIdx.x;
  if (i >= 6272 * 192) return;
  int m = i / 192, kq = (i % 192) * 4;
  int b = m / 196, pp = m % 196, py = pp / 14, px = pp % 14;
  int c = kq >> 8, rem = kq & 255, iy = rem >> 4, ix = rem & 15;
  const float4 v = *(const float4*)&x[(((size_t)(b * 3 + c) * 224 + py * 16 + iy) * 224) + px * 16 + ix];
  bf16x4 pv = {(bf16)v.x, (bf16)v.y, (bf16)v.z, (bf16)v.w};
  *(bf16x4*)&patches[(size_t)m * 768 + kq] = pv;
}

// prefill h: h[b][s][:] = pos[s] (+ cls for s==0); patch GEMM then accumulates
__global__ __launch_bounds__(256) void h_init_full(
    const float* __restrict__ cls, const float* __restrict__ pos,
    float* __restrict__ h)
{
  int i = blockIdx.x * 256 + threadIdx.x;
  if (i >= 6304 * 192) return;
  int row = i / 192, c4 = (i % 192) * 4;
  int s = row % 197;
  float4 pv = *(const float4*)&pos[(size_t)s * 768 + c4];
  if (s == 0) {
    float4 cv = *(const float4*)&cls[c4];
    pv.x += cv.x; pv.y += cv.y; pv.z += cv.z; pv.w += cv.w;
  }
  *(float4*)&h[(size_t)row * 768 + c4] = pv;
}

extern "C" void kernel_launch(void* const* d_in, const int* in_sizes, int n_in,
                              void* d_out, int out_size, void* d_ws, size_t ws_size,
                              hipStream_t stream)
{
  const float* x      = (const float*)d_in[0];
  const float* conv_w = (const float*)d_in[1];
  const float* conv_b = (const float*)d_in[2];
  const float* cls    = (const float*)d_in[3];
  const float* pos    = (const float*)d_in[4];
  const float* ln1_w  = (const float*)d_in[5];
  const float* ln1_b  = (const float*)d_in[6];
  const float* qkv_w  = (const float*)d_in[7];
  const float* qkv_b  = (const float*)d_in[8];
  const float* proj_w = (const float*)d_in[9];
  const float* proj_b = (const float*)d_in[10];
  const float* ln2_w  = (const float*)d_in[11];
  const float* ln2_b  = (const float*)d_in[12];
  const float* fc1_w  = (const float*)d_in[13];
  const float* fc1_b  = (const float*)d_in[14];
  const float* fc2_w  = (const float*)d_in[15];
  const float* fc2_b  = (const float*)d_in[16];
  const float* lnf_w  = (const float*)d_in[17];
  const float* lnf_b  = (const float*)d_in[18];
  float* out = (float*)d_out;
  (void)in_sizes; (void)n_in; (void)out_size; (void)ws_size;

  char* ws = (char*)d_ws;
  size_t off = 0;
  auto alloc = [&](size_t bytes) -> char* {
    char* p = ws + off;
    off += (bytes + 255) & ~(size_t)255;
    return p;
  };

  bf16*  convwB  = (bf16*)alloc((size_t)768 * 768 * 2);
  bf16*  qkvT    = (bf16*)alloc((size_t)12 * 2304 * 768 * 2);
  bf16*  projT   = (bf16*)alloc((size_t)12 * 768 * 768 * 2);
  bf16*  fc1T    = (bf16*)alloc((size_t)12 * 3072 * 768 * 2);
  bf16*  fc2T    = (bf16*)alloc((size_t)12 * 768 * 3072 * 2);
  bf16*  patches = (bf16*)alloc((size_t)6272 * 768 * 2);
  float* h       = (float*)alloc((size_t)6304 * 768 * 4);
  bf16*  y       = (bf16*)alloc((size_t)6304 * 768 * 2);
  bf16*  qkvB    = (bf16*)alloc((size_t)6304 * 2304 * 2);
  bf16*  obuf    = (bf16*)alloc((size_t)6304 * 768 * 2);
  bf16*  g       = (bf16*)alloc((size_t)6304 * 3072 * 2);

  // weight prep (every call: ws is re-poisoned)
  convert_bf16<<<(768 * 768 + 255) / 256, 256, 0, stream>>>(conv_w, convwB, 768 * 768);
  transpose_w<<<dim3(2304 / 32, 768 / 32, 12), 256, 0, stream>>>(qkv_w, qkvT, 768, 2304);
  transpose_w<<<dim3(768 / 32, 768 / 32, 12), 256, 0, stream>>>(proj_w, projT, 768, 768);
  transpose_w<<<dim3(3072 / 32, 768 / 32, 12), 256, 0, stream>>>(fc1_w, fc1T, 768, 3072);
  transpose_w<<<dim3(768 / 32, 3072 / 32, 12), 256, 0, stream>>>(fc2_w, fc2T, 3072, 768);

  patch_extract<<<(6272 * 192) / 256, 256, 0, stream>>>(x, patches);
  h_init_full<<<(6304 * 192 + 255) / 256, 256, 0, stream>>>(cls, pos, h);
  gemm8<EPI_PATCH><<<dim3(50, 6, 2), 512, 0, stream>>>(
      patches, convwB, conv_b, nullptr, h, 6272, 768, 768, 384);

  for (int l = 0; l < 12; l++) {
    ln_bf16<<<1576, 256, 0, stream>>>(h, ln1_w + l * 768, ln1_b + l * 768, y, 6304);
    gemm8<EPI_BF16><<<dim3(50, 18, 1), 512, 0, stream>>>(
        y, qkvT + (size_t)l * 2304 * 768, qkv_b + l * 2304, qkvB, nullptr,
        6304, 2304, 768, 768);
    attn_kernel<<<32 * 12 * 4, 256, 0, stream>>>(qkvB, obuf);
    gemm8<EPI_RESID><<<dim3(50, 6, 2), 512, 0, stream>>>(
        obuf, projT + (size_t)l * 768 * 768, proj_b + l * 768, nullptr, h,
        6304, 768, 768, 384);
    ln_bf16<<<1576, 256, 0, stream>>>(h, ln2_w + l * 768, ln2_b + l * 768, y, 6304);
    gemm8<EPI_GELU><<<dim3(50, 24, 1), 512, 0, stream>>>(
        y, fc1T + (size_t)l * 3072 * 768, fc1_b + l * 3072, g, nullptr,
        6304, 3072, 768, 768);
    gemm8<EPI_RESID><<<dim3(50, 6, 2), 512, 0, stream>>>(
        g, fc2T + (size_t)l * 768 * 3072, fc2_b + l * 768, nullptr, h,
        6304, 768, 3072, 1536);
  }
  ln_final<<<8, 256, 0, stream>>>(h, lnf_w, lnf_b, out);
}